// Round 1
// baseline (511.909 us; speedup 1.0000x reference)
//
#include <hip/hip_runtime.h>
#include <math.h>

// cSE channel self-attention, fp32 baseline.
// x: [N=4][C=128][S=110592] f32.  out: same shape.
// energy = Q Q^T per batch; attn = softmax(rowmax - energy) == exp(rowmin - e)/sum;
// out = attn @ Q.

static constexpr int CN = 128;        // channels
static constexpr int SN = 110592;     // 48*48*48
static constexpr int NBATCH = 4;
static constexpr int GRAM_BLOCKS = 64;            // s-slices per batch
static constexpr int GRAM_S_PER_BLOCK = SN / GRAM_BLOCKS;   // 1728
static constexpr int GRAM_CHUNKS = GRAM_S_PER_BLOCK / 64;   // 27

// ---------------- K1: Gram partial sums ----------------
// grid (GRAM_BLOCKS, NBATCH), block 256.
// Each block: batch n, s in [bx*1728, bx*1728+1728), 27 chunks of 64.
// LDS tile [s][c] so compute reads 8 consecutive channels as 2x float4.
template <bool ATOMIC>
__global__ __launch_bounds__(256) void gram_kernel(const float* __restrict__ x,
                                                   float* __restrict__ dst) {
    __shared__ float lds[64][CN];   // 32 KB
    const int bx = blockIdx.x;
    const int n  = blockIdx.y;
    const int tid = threadIdx.x;
    const int ty = tid >> 4, tx = tid & 15;
    const int i0 = ty * 8, j0 = tx * 8;

    const float* gq = x + (size_t)n * CN * SN;
    const int s_base = bx * GRAM_S_PER_BLOCK;

    float acc[8][8];
#pragma unroll
    for (int i = 0; i < 8; ++i)
#pragma unroll
        for (int j = 0; j < 8; ++j) acc[i][j] = 0.f;

    float4 pf[8];
    auto load_chunk = [&](int it) {
        const float* base = gq + s_base + it * 64 + (tx << 2);
#pragma unroll
        for (int k = 0; k < 8; ++k) {
            int c = ty + (k << 4);
            pf[k] = *reinterpret_cast<const float4*>(base + (size_t)c * SN);
        }
    };

    load_chunk(0);
    for (int it = 0; it < GRAM_CHUNKS; ++it) {
        __syncthreads();   // previous chunk's LDS reads done
#pragma unroll
        for (int k = 0; k < 8; ++k) {
            int c = ty + (k << 4);
            const int s4 = tx << 2;
            lds[s4 + 0][c] = pf[k].x;
            lds[s4 + 1][c] = pf[k].y;
            lds[s4 + 2][c] = pf[k].z;
            lds[s4 + 3][c] = pf[k].w;
        }
        __syncthreads();
        if (it < GRAM_CHUNKS - 1) load_chunk(it + 1);   // overlap with compute

#pragma unroll 4
        for (int s = 0; s < 64; ++s) {
            float a[8], b[8];
            *reinterpret_cast<float4*>(a)     = *reinterpret_cast<const float4*>(&lds[s][i0]);
            *reinterpret_cast<float4*>(a + 4) = *reinterpret_cast<const float4*>(&lds[s][i0 + 4]);
            *reinterpret_cast<float4*>(b)     = *reinterpret_cast<const float4*>(&lds[s][j0]);
            *reinterpret_cast<float4*>(b + 4) = *reinterpret_cast<const float4*>(&lds[s][j0 + 4]);
#pragma unroll
            for (int i = 0; i < 8; ++i)
#pragma unroll
                for (int j = 0; j < 8; ++j)
                    acc[i][j] = fmaf(a[i], b[j], acc[i][j]);
        }
    }

    if (ATOMIC) {
        float* E = dst + (size_t)n * CN * CN;
#pragma unroll
        for (int i = 0; i < 8; ++i)
#pragma unroll
            for (int j = 0; j < 8; ++j)
                atomicAdd(&E[(i0 + i) * CN + j0 + j], acc[i][j]);
    } else {
        float* P = dst + (size_t)(n * GRAM_BLOCKS + bx) * (CN * CN);
#pragma unroll
        for (int i = 0; i < 8; ++i) {
            *reinterpret_cast<float4*>(&P[(i0 + i) * CN + j0])     = *reinterpret_cast<float4*>(&acc[i][0]);
            *reinterpret_cast<float4*>(&P[(i0 + i) * CN + j0 + 4]) = *reinterpret_cast<float4*>(&acc[i][4]);
        }
    }
}

// ---------------- K1b: reduce partials ----------------
// grid (NBATCH*CN*CN/256), block 256. Deterministic fixed-order sum.
__global__ __launch_bounds__(256) void reduce_kernel(const float* __restrict__ part,
                                                     float* __restrict__ energy) {
    const int t = blockIdx.x * 256 + threadIdx.x;     // 0..65535
    const int n = t >> 14;                            // 16384 per batch
    const int rem = t & 16383;
    const float* p = part + (size_t)n * GRAM_BLOCKS * (CN * CN) + rem;
    float s = 0.f;
#pragma unroll 8
    for (int k = 0; k < GRAM_BLOCKS; ++k) s += p[(size_t)k * (CN * CN)];
    energy[t] = s;
}

// ---------------- K2: softmax (softmin over energy) ----------------
// grid (CN, NBATCH), block 64 (one wave per row).
// attention[i][j] = exp(min_j e - e_ij) / sum.  Writes att^T: att_t[n][j][i].
__global__ void softmax_kernel(const float* __restrict__ energy,
                               float* __restrict__ att_t) {
    const int i = blockIdx.x;
    const int n = blockIdx.y;
    const int l = threadIdx.x;   // 0..63
    const float* E = energy + ((size_t)n * CN + i) * CN;
    const float e0 = E[l], e1 = E[l + 64];
    float m = fminf(e0, e1);
#pragma unroll
    for (int off = 32; off > 0; off >>= 1) m = fminf(m, __shfl_xor(m, off));
    const float p0 = expf(m - e0);
    const float p1 = expf(m - e1);
    float s = p0 + p1;
#pragma unroll
    for (int off = 32; off > 0; off >>= 1) s += __shfl_xor(s, off);
    const float inv = 1.f / s;
    att_t[((size_t)n * CN + l) * CN + i]      = p0 * inv;
    att_t[((size_t)n * CN + l + 64) * CN + i] = p1 * inv;
}

// ---------------- K3: out = attn @ Q ----------------
// grid (64 s-blocks, 2 i-halves, NBATCH), block 256.
// LDS: att^T slab [128 j][64 i] (32KB) + q chunk [128 j][64 s] (32KB) = 64KB.
static constexpr int PV_SBLOCKS = 64;
static constexpr int PV_S_PER_BLOCK = SN / PV_SBLOCKS;   // 1728
static constexpr int PV_CHUNKS = PV_S_PER_BLOCK / 64;    // 27

__global__ __launch_bounds__(256) void pv_kernel(const float* __restrict__ x,
                                                 const float* __restrict__ att_t,
                                                 float* __restrict__ out) {
    __shared__ float att[CN][64];   // att[j][local i]
    __shared__ float qs[CN][64];    // qs[j][local s]
    const int bx = blockIdx.x;
    const int ih = blockIdx.y;
    const int n  = blockIdx.z;
    const int tid = threadIdx.x;
    const int ty = tid >> 4, tx = tid & 15;

    const float* gq = x + (size_t)n * CN * SN;
    const int s_base = bx * PV_S_PER_BLOCK;

    // stage att^T slab: rows j=0..127, local cols = ih*64..+64
    {
        const float* src = att_t + (size_t)n * CN * CN + ih * 64;
#pragma unroll
        for (int k = 0; k < 8; ++k) {
            const int idx = tid + (k << 8);
            const int j  = idx >> 4;           // 16 float4 per row
            const int ii = (idx & 15) << 2;
            *reinterpret_cast<float4*>(&att[j][ii]) =
                *reinterpret_cast<const float4*>(src + (size_t)j * CN + ii);
        }
    }

    float4 pf[8];
    auto load_chunk = [&](int it) {
        const float* base = gq + s_base + it * 64 + (tx << 2);
#pragma unroll
        for (int k = 0; k < 8; ++k) {
            int c = ty + (k << 4);
            pf[k] = *reinterpret_cast<const float4*>(base + (size_t)c * SN);
        }
    };

    load_chunk(0);
    for (int it = 0; it < PV_CHUNKS; ++it) {
        __syncthreads();   // covers att staging (it==0) and prior qs reads
#pragma unroll
        for (int k = 0; k < 8; ++k) {
            int c = ty + (k << 4);
            *reinterpret_cast<float4*>(&qs[c][tx << 2]) = pf[k];
        }
        __syncthreads();
        if (it < PV_CHUNKS - 1) load_chunk(it + 1);

        float acc[4][4];
#pragma unroll
        for (int r = 0; r < 4; ++r)
#pragma unroll
            for (int c = 0; c < 4; ++c) acc[r][c] = 0.f;

#pragma unroll 4
        for (int j = 0; j < CN; ++j) {
            const float4 av = *reinterpret_cast<const float4*>(&att[j][ty << 2]);
            const float4 qv = *reinterpret_cast<const float4*>(&qs[j][tx << 2]);
            acc[0][0] = fmaf(av.x, qv.x, acc[0][0]);
            acc[0][1] = fmaf(av.x, qv.y, acc[0][1]);
            acc[0][2] = fmaf(av.x, qv.z, acc[0][2]);
            acc[0][3] = fmaf(av.x, qv.w, acc[0][3]);
            acc[1][0] = fmaf(av.y, qv.x, acc[1][0]);
            acc[1][1] = fmaf(av.y, qv.y, acc[1][1]);
            acc[1][2] = fmaf(av.y, qv.z, acc[1][2]);
            acc[1][3] = fmaf(av.y, qv.w, acc[1][3]);
            acc[2][0] = fmaf(av.z, qv.x, acc[2][0]);
            acc[2][1] = fmaf(av.z, qv.y, acc[2][1]);
            acc[2][2] = fmaf(av.z, qv.z, acc[2][2]);
            acc[2][3] = fmaf(av.z, qv.w, acc[2][3]);
            acc[3][0] = fmaf(av.w, qv.x, acc[3][0]);
            acc[3][1] = fmaf(av.w, qv.y, acc[3][1]);
            acc[3][2] = fmaf(av.w, qv.z, acc[3][2]);
            acc[3][3] = fmaf(av.w, qv.w, acc[3][3]);
        }

        float* o = out + ((size_t)n * CN + ih * 64 + (ty << 2)) * SN
                       + s_base + it * 64 + (tx << 2);
#pragma unroll
        for (int r = 0; r < 4; ++r)
            *reinterpret_cast<float4*>(o + (size_t)r * SN) =
                *reinterpret_cast<float4*>(&acc[r][0]);
    }
}

extern "C" void kernel_launch(void* const* d_in, const int* in_sizes, int n_in,
                              void* d_out, int out_size, void* d_ws, size_t ws_size,
                              hipStream_t stream) {
    (void)in_sizes; (void)n_in; (void)out_size;
    const float* x = (const float*)d_in[0];
    float* out = (float*)d_out;

    // ws layout: [energy 256KB][att_t 256KB][partials 16MB]
    float* energy = (float*)d_ws;
    float* att_t  = energy + (size_t)NBATCH * CN * CN;
    float* part   = att_t + (size_t)NBATCH * CN * CN;
    const size_t need_bytes =
        (size_t)(2 * NBATCH * CN * CN) * sizeof(float) +
        (size_t)NBATCH * GRAM_BLOCKS * CN * CN * sizeof(float);

    if (ws_size >= need_bytes) {
        // deterministic partial-sum path
        gram_kernel<false><<<dim3(GRAM_BLOCKS, NBATCH), 256, 0, stream>>>(x, part);
        reduce_kernel<<<dim3(NBATCH * CN * CN / 256), 256, 0, stream>>>(part, energy);
    } else {
        // atomic fallback (small ws)
        hipMemsetAsync(energy, 0, (size_t)NBATCH * CN * CN * sizeof(float), stream);
        gram_kernel<true><<<dim3(GRAM_BLOCKS, NBATCH), 256, 0, stream>>>(x, energy);
    }
    softmax_kernel<<<dim3(CN, NBATCH), 64, 0, stream>>>(energy, att_t);
    pv_kernel<<<dim3(PV_SBLOCKS, 2, NBATCH), 256, 0, stream>>>(x, att_t, out);
}

// Round 2
// 172.144 us; speedup vs baseline: 2.9737x; 2.9737x over previous
//
#include <hip/hip_runtime.h>
#include <math.h>

// cSE channel self-attention, bf16-MFMA hi/lo version.
// x: [N=4][C=128][S=110592] f32.  out: same shape f32.
// energy = Q Q^T; attn_ij = exp(rowmin - e_ij)/sum (== reference softmax(max-e));
// out = attn @ Q.

static constexpr int CN = 128;
static constexpr int SN = 110592;      // 48^3
static constexpr int NB = 4;

static constexpr int GB = 64;          // gram K-slices per batch
static constexpr int GSL = SN / GB;    // 1728
static constexpr int GCH = GSL / 64;   // 27 chunks of K=64

static constexpr int PB = 432;         // pv s-blocks per batch (256 s each)
static constexpr int PCH = 4;          // chunks of 64 s per block

typedef float  f32x4  __attribute__((ext_vector_type(4)));
typedef short  bf16x8 __attribute__((ext_vector_type(8)));
typedef unsigned short u16x8 __attribute__((ext_vector_type(8)));
typedef unsigned short u16x4 __attribute__((ext_vector_type(4)));

// f32 -> (hi bf16, lo bf16) round-to-nearest-even, packed lo<<16|hi
__device__ __forceinline__ unsigned int splitpack(float v) {
    unsigned int u = __float_as_uint(v);
    unsigned int h = (u + 0x7fffu + ((u >> 16) & 1u)) >> 16;
    float lf = v - __uint_as_float(h << 16);
    unsigned int ul = __float_as_uint(lf);
    unsigned int l = (ul + 0x7fffu + ((ul >> 16) & 1u)) >> 16;
    return (l << 16) | (h & 0xffffu);
}
__device__ __forceinline__ unsigned short f2bh(float v) {
    unsigned int u = __float_as_uint(v);
    return (unsigned short)((u + 0x7fffu + ((u >> 16) & 1u)) >> 16);
}
__device__ __forceinline__ float bh2f(unsigned short h) {
    return __uint_as_float((unsigned int)h << 16);
}

// swizzled LDS fragment read: 8 consecutive bf16 along k at given row
__device__ __forceinline__ bf16x8 ldsfrag(const unsigned short* base, int row, int kbyte, int pitchB) {
    const char* p = reinterpret_cast<const char*>(base) + row * pitchB + (kbyte ^ ((row & 7) << 4));
    return *reinterpret_cast<const bf16x8*>(p);
}
__device__ __forceinline__ f32x4 mm(bf16x8 a, bf16x8 b, f32x4 c) {
    return __builtin_amdgcn_mfma_f32_16x16x32_bf16(a, b, c, 0, 0, 0);
}

// ---------------- K1: Gram via MFMA, hi/lo split ----------------
// grid (GB, NB), block 512 (8 waves). Each block: K-slice of 1728, 27 chunks of 64.
// LDS: [128 c][64 k] bf16 hi + lo, pitch 128B, XOR-swizzled.
template <bool ATOMIC>
__global__ __launch_bounds__(512) void gram_mfma(const float* __restrict__ x,
                                                 float* __restrict__ dst) {
    __shared__ __align__(16) unsigned short lh[CN * 64];
    __shared__ __align__(16) unsigned short ll[CN * 64];
    const int bx = blockIdx.x, n = blockIdx.y;
    const int tid = threadIdx.x;
    const int lane = tid & 63;
    const int w = tid >> 6;                // 0..7
    const int wr = w >> 2, wc = w & 3;     // wave grid 2x4
    const int ra = lane & 15, kg = lane >> 4;

    // staging mapping: thread -> (channel c, 16 consecutive k)
    const int c  = tid >> 2;               // 0..127
    const int ks = (tid & 3) << 4;         // 0,16,32,48
    const float* gq = x + (size_t)n * CN * SN + (size_t)c * SN + bx * GSL;

    f32x4 acc[4][2];
#pragma unroll
    for (int a = 0; a < 4; ++a)
#pragma unroll
        for (int b = 0; b < 2; ++b) acc[a][b] = (f32x4){0.f, 0.f, 0.f, 0.f};

    float4 st[4];
    auto load_chunk = [&](int t) {
        const float4* p = reinterpret_cast<const float4*>(gq + t * 64 + ks);
        st[0] = p[0]; st[1] = p[1]; st[2] = p[2]; st[3] = p[3];
    };

    auto stage = [&]() {
        u16x8 ha, hb, la, lb;
        unsigned int p;
#define CV8(hv, lv, i, val) { p = splitpack(val); hv[i] = (unsigned short)(p & 0xffffu); lv[i] = (unsigned short)(p >> 16); }
        CV8(ha, la, 0, st[0].x) CV8(ha, la, 1, st[0].y) CV8(ha, la, 2, st[0].z) CV8(ha, la, 3, st[0].w)
        CV8(ha, la, 4, st[1].x) CV8(ha, la, 5, st[1].y) CV8(ha, la, 6, st[1].z) CV8(ha, la, 7, st[1].w)
        CV8(hb, lb, 0, st[2].x) CV8(hb, lb, 1, st[2].y) CV8(hb, lb, 2, st[2].z) CV8(hb, lb, 3, st[2].w)
        CV8(hb, lb, 4, st[3].x) CV8(hb, lb, 5, st[3].y) CV8(hb, lb, 6, st[3].z) CV8(hb, lb, 7, st[3].w)
#undef CV8
        char* ph = reinterpret_cast<char*>(lh) + c * 128;
        char* pl = reinterpret_cast<char*>(ll) + c * 128;
        const int sw = (c & 7) << 4;
        const int k2 = ks * 2;
        *reinterpret_cast<u16x8*>(ph + (k2 ^ sw))        = ha;
        *reinterpret_cast<u16x8*>(ph + ((k2 + 16) ^ sw)) = hb;
        *reinterpret_cast<u16x8*>(pl + (k2 ^ sw))        = la;
        *reinterpret_cast<u16x8*>(pl + ((k2 + 16) ^ sw)) = lb;
    };

    auto compute = [&]() {
#pragma unroll
        for (int kk = 0; kk < 2; ++kk) {
            const int kb = kk * 64 + (kg << 4);
            bf16x8 ah[4], al[4], bh[2], bl[2];
#pragma unroll
            for (int it = 0; it < 4; ++it) {
                const int row = wr * 64 + it * 16 + ra;
                ah[it] = ldsfrag(lh, row, kb, 128);
                al[it] = ldsfrag(ll, row, kb, 128);
            }
#pragma unroll
            for (int jt = 0; jt < 2; ++jt) {
                const int row = wc * 32 + jt * 16 + ra;
                bh[jt] = ldsfrag(lh, row, kb, 128);
                bl[jt] = ldsfrag(ll, row, kb, 128);
            }
#pragma unroll
            for (int it = 0; it < 4; ++it)
#pragma unroll
                for (int jt = 0; jt < 2; ++jt) {
                    acc[it][jt] = mm(ah[it], bh[jt], acc[it][jt]);
                    acc[it][jt] = mm(ah[it], bl[jt], acc[it][jt]);
                    acc[it][jt] = mm(al[it], bh[jt], acc[it][jt]);
                }
        }
    };

    load_chunk(0);
    for (int t = 0; t < GCH; ++t) {
        if (t) __syncthreads();        // prev chunk's LDS reads done
        stage();
        __syncthreads();
        if (t < GCH - 1) load_chunk(t + 1);   // prefetch overlaps MFMA
        compute();
    }

    // epilogue: C/D map row=(lane>>4)*4+q, col=lane&15
    const int q4 = kg << 2;
    if (!ATOMIC) {
        float* P = dst + (size_t)(n * GB + bx) * (CN * CN);
#pragma unroll
        for (int it = 0; it < 4; ++it)
#pragma unroll
            for (int jt = 0; jt < 2; ++jt)
#pragma unroll
                for (int q = 0; q < 4; ++q)
                    P[(wr * 64 + it * 16 + q4 + q) * CN + wc * 32 + jt * 16 + ra] = acc[it][jt][q];
    } else {
        float* E = dst + (size_t)n * CN * CN;
#pragma unroll
        for (int it = 0; it < 4; ++it)
#pragma unroll
            for (int jt = 0; jt < 2; ++jt)
#pragma unroll
                for (int q = 0; q < 4; ++q)
                    atomicAdd(&E[(wr * 64 + it * 16 + q4 + q) * CN + wc * 32 + jt * 16 + ra], acc[it][jt][q]);
    }
}

// ---------------- K1b: reduce partials (deterministic) ----------------
__global__ __launch_bounds__(256) void reduce_kernel(const float* __restrict__ part,
                                                     float* __restrict__ energy) {
    const int t = blockIdx.x * 256 + threadIdx.x;   // 0..65535
    const int n = t >> 14;
    const int rem = t & 16383;
    const float* p = part + (size_t)n * GB * (CN * CN) + rem;
    float s = 0.f;
#pragma unroll 8
    for (int k = 0; k < GB; ++k) s += p[(size_t)k * (CN * CN)];
    energy[t] = s;
}

// ---------------- K2: softmax -> bf16 hi/lo attention, natural [i][j] ----------------
__global__ void softmax_kernel(const float* __restrict__ energy,
                               unsigned short* __restrict__ att_h,
                               unsigned short* __restrict__ att_l) {
    const int i = blockIdx.x, n = blockIdx.y, l = threadIdx.x;
    const float* E = energy + ((size_t)n * CN + i) * CN;
    const float e0 = E[l], e1 = E[l + 64];
    float m = fminf(e0, e1);
#pragma unroll
    for (int off = 32; off > 0; off >>= 1) m = fminf(m, __shfl_xor(m, off));
    const float p0 = expf(m - e0);
    const float p1 = expf(m - e1);
    float s = p0 + p1;
#pragma unroll
    for (int off = 32; off > 0; off >>= 1) s += __shfl_xor(s, off);
    const float inv = 1.f / s;
    const float a0 = p0 * inv, a1 = p1 * inv;
    const size_t o = ((size_t)n * CN + i) * CN;
    unsigned int q0 = splitpack(a0), q1 = splitpack(a1);
    att_h[o + l]      = (unsigned short)(q0 & 0xffffu);
    att_l[o + l]      = (unsigned short)(q0 >> 16);
    att_h[o + l + 64] = (unsigned short)(q1 & 0xffffu);
    att_l[o + l + 64] = (unsigned short)(q1 >> 16);
}

// ---------------- K3: out = attn @ Q via MFMA ----------------
// grid (PB, NB), block 512. Per block: 256 s (4 chunks of 64).
// A (attn rows for this wave) held in registers, loaded from global once.
// LDS: q transposed [64 s][128 j] bf16 hi+lo, pitch 256B, XOR-swizzled.
__global__ __launch_bounds__(512) void pv_mfma(const float* __restrict__ x,
                                               const unsigned short* __restrict__ att_h,
                                               const unsigned short* __restrict__ att_l,
                                               float* __restrict__ out) {
    __shared__ __align__(16) unsigned short qh[64 * CN];
    __shared__ __align__(16) unsigned short ql[64 * CN];
    const int bx = blockIdx.x, n = blockIdx.y;
    const int tid = threadIdx.x;
    const int lane = tid & 63;
    const int w = tid >> 6;                 // wave -> i-tile (rows w*16..w*16+15)
    const int ra = lane & 15, kg = lane >> 4;

    // A-fragments from global (attn just written; L2-resident)
    bf16x8 a_h[4], a_l[4];
    {
        const size_t rowoff = ((size_t)n * CN + w * 16 + ra) * CN + kg * 8;
        const unsigned short* Ah = att_h + rowoff;
        const unsigned short* Al = att_l + rowoff;
#pragma unroll
        for (int kk = 0; kk < 4; ++kk) {
            a_h[kk] = *reinterpret_cast<const bf16x8*>(Ah + kk * 32);
            a_l[kk] = *reinterpret_cast<const bf16x8*>(Al + kk * 32);
        }
    }

    // staging mapping: thread -> 4x4 micro-block (j0..j0+3, s0..s0+3)
    const int sq4 = tid & 15;               // float4 col within 64-s chunk
    const int j0  = (tid >> 4) * 4;         // 0..124
    const int s0  = sq4 * 4;
    const float* gx = x + (size_t)n * CN * SN;
    const int sbase = bx * (PCH * 64);

    float4 st[4];
    auto load_chunk = [&](int sb) {
#pragma unroll
        for (int r = 0; r < 4; ++r)
            st[r] = *reinterpret_cast<const float4*>(gx + (size_t)(j0 + r) * SN + sb + s0);
    };

    auto wrow = [&](int s, float v0, float v1, float v2, float v3) {
        u16x4 hv, lv;
        unsigned int p;
        p = splitpack(v0); hv[0] = (unsigned short)(p & 0xffffu); lv[0] = (unsigned short)(p >> 16);
        p = splitpack(v1); hv[1] = (unsigned short)(p & 0xffffu); lv[1] = (unsigned short)(p >> 16);
        p = splitpack(v2); hv[2] = (unsigned short)(p & 0xffffu); lv[2] = (unsigned short)(p >> 16);
        p = splitpack(v3); hv[3] = (unsigned short)(p & 0xffffu); lv[3] = (unsigned short)(p >> 16);
        const int off = s * 256 + ((j0 * 2) ^ ((s & 7) << 4));
        *reinterpret_cast<u16x4*>(reinterpret_cast<char*>(qh) + off) = hv;
        *reinterpret_cast<u16x4*>(reinterpret_cast<char*>(ql) + off) = lv;
    };
    auto stage = [&]() {
        wrow(s0 + 0, st[0].x, st[1].x, st[2].x, st[3].x);
        wrow(s0 + 1, st[0].y, st[1].y, st[2].y, st[3].y);
        wrow(s0 + 2, st[0].z, st[1].z, st[2].z, st[3].z);
        wrow(s0 + 3, st[0].w, st[1].w, st[2].w, st[3].w);
    };

    auto compute = [&](int sb) {
#pragma unroll
        for (int stile = 0; stile < 4; ++stile) {
            f32x4 acc = (f32x4){0.f, 0.f, 0.f, 0.f};
            const int srow = stile * 16 + ra;
#pragma unroll
            for (int kk = 0; kk < 4; ++kk) {
                const int kb = kk * 64 + (kg << 4);
                bf16x8 bh = ldsfrag(qh, srow, kb, 256);
                bf16x8 bl = ldsfrag(ql, srow, kb, 256);
                acc = mm(a_h[kk], bh, acc);
                acc = mm(a_h[kk], bl, acc);
                acc = mm(a_l[kk], bh, acc);
            }
            float* o = out + ((size_t)n * CN + w * 16 + (kg << 2)) * SN + sb + stile * 16 + ra;
#pragma unroll
            for (int q = 0; q < 4; ++q) o[(size_t)q * SN] = acc[q];
        }
    };

    load_chunk(sbase);
    for (int t = 0; t < PCH; ++t) {
        if (t) __syncthreads();
        stage();
        __syncthreads();
        if (t < PCH - 1) load_chunk(sbase + (t + 1) * 64);
        compute(sbase + t * 64);
    }
}

extern "C" void kernel_launch(void* const* d_in, const int* in_sizes, int n_in,
                              void* d_out, int out_size, void* d_ws, size_t ws_size,
                              hipStream_t stream) {
    (void)in_sizes; (void)n_in; (void)out_size;
    const float* x = (const float*)d_in[0];
    float* out = (float*)d_out;

    // ws: [energy 256KB][att_h 128KB][att_l 128KB][partials 16MB]
    float* energy = (float*)d_ws;
    unsigned short* att_h = (unsigned short*)(energy + (size_t)NB * CN * CN);
    unsigned short* att_l = att_h + (size_t)NB * CN * CN;
    float* part = (float*)(att_l + (size_t)NB * CN * CN);
    const size_t need =
        (size_t)NB * CN * CN * sizeof(float) +
        (size_t)NB * CN * CN * 2 * sizeof(unsigned short) +
        (size_t)NB * GB * CN * CN * sizeof(float);

    if (ws_size >= need) {
        gram_mfma<false><<<dim3(GB, NB), 512, 0, stream>>>(x, part);
        reduce_kernel<<<dim3(NB * CN * CN / 256), 256, 0, stream>>>(part, energy);
    } else {
        hipMemsetAsync(energy, 0, (size_t)NB * CN * CN * sizeof(float), stream);
        gram_mfma<true><<<dim3(GB, NB), 512, 0, stream>>>(x, energy);
    }
    softmax_kernel<<<dim3(CN, NB), 64, 0, stream>>>(energy, att_h, att_l);
    pv_mfma<<<dim3(PB, NB), 512, 0, stream>>>(x, att_h, att_l, out);
}

// Round 3
// 142.707 us; speedup vs baseline: 3.5871x; 1.2063x over previous
//
#include <hip/hip_runtime.h>
#include <math.h>

// cSE channel self-attention, bf16-MFMA hi/lo, double-buffered.
// x: [N=4][C=128][S=110592] f32.  out: same shape f32.
// energy = Q Q^T; attn_ij = exp(rowmin - e_ij)/sum (== reference softmax(max-e));
// out = attn @ Q.

static constexpr int CN = 128;
static constexpr int SN = 110592;      // 48^3
static constexpr int NB = 4;

static constexpr int GB = 64;          // gram K-slices per batch (256 blocks = 1/CU)
static constexpr int GSL = SN / GB;    // 1728
static constexpr int GCH = GSL / 64;   // 27 chunks of K=64

static constexpr int PB = 432;         // pv s-blocks per batch (256 s each)
static constexpr int PCH = 4;          // chunks of 64 s per block

typedef float  f32x4  __attribute__((ext_vector_type(4)));
typedef short  bf16x8 __attribute__((ext_vector_type(8)));
typedef unsigned short u16x8 __attribute__((ext_vector_type(8)));
typedef unsigned short u16x4 __attribute__((ext_vector_type(4)));

// f32 -> (hi bf16, lo bf16) round-to-nearest-even, packed lo<<16|hi
__device__ __forceinline__ unsigned int splitpack(float v) {
    unsigned int u = __float_as_uint(v);
    unsigned int h = (u + 0x7fffu + ((u >> 16) & 1u)) >> 16;
    float lf = v - __uint_as_float(h << 16);
    unsigned int ul = __float_as_uint(lf);
    unsigned int l = (ul + 0x7fffu + ((ul >> 16) & 1u)) >> 16;
    return (l << 16) | (h & 0xffffu);
}
__device__ __forceinline__ unsigned short f2bh(float v) {
    unsigned int u = __float_as_uint(v);
    return (unsigned short)((u + 0x7fffu + ((u >> 16) & 1u)) >> 16);
}

// swizzled LDS fragment read: 16 B along k at given row
__device__ __forceinline__ bf16x8 ldsfrag(const unsigned short* base, int row, int kbyte, int pitchB) {
    const char* p = reinterpret_cast<const char*>(base) + row * pitchB + (kbyte ^ ((row & 7) << 4));
    return *reinterpret_cast<const bf16x8*>(p);
}
__device__ __forceinline__ f32x4 mm(bf16x8 a, bf16x8 b, f32x4 c) {
    return __builtin_amdgcn_mfma_f32_16x16x32_bf16(a, b, c, 0, 0, 0);
}

// ---------------- K1: Gram via MFMA, hi/lo split, double-buffered ----------------
// grid (GB, NB), block 512 (8 waves). Each block: K-slice of 1728, 27 chunks of 64.
// LDS: 2 x ([128 c][64 k] bf16 hi + lo), pitch 128B, XOR-swizzled.  64 KB total.
template <bool ATOMIC>
__global__ __launch_bounds__(512, 2) void gram_mfma(const float* __restrict__ x,
                                                    float* __restrict__ dst) {
    __shared__ __align__(16) unsigned short lh[2][CN * 64];
    __shared__ __align__(16) unsigned short ll[2][CN * 64];
    const int bx = blockIdx.x, n = blockIdx.y;
    const int tid = threadIdx.x;
    const int lane = tid & 63;
    const int w = tid >> 6;                // 0..7
    const int wr = w >> 2, wc = w & 3;     // wave grid 2x4
    const int ra = lane & 15, kg = lane >> 4;

    // staging mapping: thread -> (channel c, 16 consecutive k)
    const int c  = tid >> 2;               // 0..127
    const int ks = (tid & 3) << 4;         // 0,16,32,48
    const float* gq = x + (size_t)n * CN * SN + (size_t)c * SN + bx * GSL;

    f32x4 acc[4][2];
#pragma unroll
    for (int a = 0; a < 4; ++a)
#pragma unroll
        for (int b = 0; b < 2; ++b) acc[a][b] = (f32x4){0.f, 0.f, 0.f, 0.f};

    float4 st[4];
    auto load_chunk = [&](int t) {
        const float4* p = reinterpret_cast<const float4*>(gq + t * 64 + ks);
        st[0] = p[0]; st[1] = p[1]; st[2] = p[2]; st[3] = p[3];
    };

    auto stage = [&](int buf) {
        u16x8 ha, hb, la, lb;
        unsigned int p;
#define CV8(hv, lv, i, val) { p = splitpack(val); hv[i] = (unsigned short)(p & 0xffffu); lv[i] = (unsigned short)(p >> 16); }
        CV8(ha, la, 0, st[0].x) CV8(ha, la, 1, st[0].y) CV8(ha, la, 2, st[0].z) CV8(ha, la, 3, st[0].w)
        CV8(ha, la, 4, st[1].x) CV8(ha, la, 5, st[1].y) CV8(ha, la, 6, st[1].z) CV8(ha, la, 7, st[1].w)
        CV8(hb, lb, 0, st[2].x) CV8(hb, lb, 1, st[2].y) CV8(hb, lb, 2, st[2].z) CV8(hb, lb, 3, st[2].w)
        CV8(hb, lb, 4, st[3].x) CV8(hb, lb, 5, st[3].y) CV8(hb, lb, 6, st[3].z) CV8(hb, lb, 7, st[3].w)
#undef CV8
        char* ph = reinterpret_cast<char*>(lh[buf]) + c * 128;
        char* pl = reinterpret_cast<char*>(ll[buf]) + c * 128;
        const int sw = (c & 7) << 4;
        const int k2 = ks * 2;
        *reinterpret_cast<u16x8*>(ph + (k2 ^ sw))        = ha;
        *reinterpret_cast<u16x8*>(ph + ((k2 + 16) ^ sw)) = hb;
        *reinterpret_cast<u16x8*>(pl + (k2 ^ sw))        = la;
        *reinterpret_cast<u16x8*>(pl + ((k2 + 16) ^ sw)) = lb;
    };

    auto compute = [&](int buf) {
        const unsigned short* LH = lh[buf];
        const unsigned short* LL = ll[buf];
#pragma unroll
        for (int kk = 0; kk < 2; ++kk) {
            const int kb = kk * 64 + (kg << 4);
            bf16x8 ah[4], al[4], bh[2], bl[2];
#pragma unroll
            for (int it = 0; it < 4; ++it) {
                const int row = wr * 64 + it * 16 + ra;
                ah[it] = ldsfrag(LH, row, kb, 128);
                al[it] = ldsfrag(LL, row, kb, 128);
            }
#pragma unroll
            for (int jt = 0; jt < 2; ++jt) {
                const int row = wc * 32 + jt * 16 + ra;
                bh[jt] = ldsfrag(LH, row, kb, 128);
                bl[jt] = ldsfrag(LL, row, kb, 128);
            }
#pragma unroll
            for (int it = 0; it < 4; ++it)
#pragma unroll
                for (int jt = 0; jt < 2; ++jt) {
                    acc[it][jt] = mm(ah[it], bh[jt], acc[it][jt]);
                    acc[it][jt] = mm(ah[it], bl[jt], acc[it][jt]);
                    acc[it][jt] = mm(al[it], bh[jt], acc[it][jt]);
                }
        }
    };

    load_chunk(0);
    for (int t = 0; t < GCH; ++t) {
        stage(t & 1);
        if (t < GCH - 1) load_chunk(t + 1);   // prefetch overlaps MFMA
        __syncthreads();                      // single barrier per chunk (dbuf)
        compute(t & 1);
    }

    // epilogue: C/D map row=(lane>>4)*4+q, col=lane&15
    const int q4 = kg << 2;
    if (!ATOMIC) {
        float* P = dst + (size_t)(n * GB + bx) * (CN * CN);
#pragma unroll
        for (int it = 0; it < 4; ++it)
#pragma unroll
            for (int jt = 0; jt < 2; ++jt)
#pragma unroll
                for (int q = 0; q < 4; ++q)
                    P[(wr * 64 + it * 16 + q4 + q) * CN + wc * 32 + jt * 16 + ra] = acc[it][jt][q];
    } else {
        float* E = dst + (size_t)n * CN * CN;
#pragma unroll
        for (int it = 0; it < 4; ++it)
#pragma unroll
            for (int jt = 0; jt < 2; ++jt)
#pragma unroll
                for (int q = 0; q < 4; ++q)
                    atomicAdd(&E[(wr * 64 + it * 16 + q4 + q) * CN + wc * 32 + jt * 16 + ra], acc[it][jt][q]);
    }
}

// ---------------- K2: fused reduce + softmin -> bf16 hi/lo attention ----------------
// grid (CN, NB), block 64 (one wave per row). Deterministic fixed-order k sum.
template <bool REDUCE>
__global__ void finish_kernel(const float* __restrict__ src,
                              unsigned short* __restrict__ att_h,
                              unsigned short* __restrict__ att_l) {
    const int i = blockIdx.x, n = blockIdx.y, l = threadIdx.x;
    float e0, e1;
    if (REDUCE) {
        const float* p = src + (size_t)n * GB * (CN * CN) + i * CN;
        e0 = 0.f; e1 = 0.f;
#pragma unroll 8
        for (int k = 0; k < GB; ++k) {
            e0 += p[(size_t)k * (CN * CN) + l];
            e1 += p[(size_t)k * (CN * CN) + l + 64];
        }
    } else {
        const float* E = src + ((size_t)n * CN + i) * CN;
        e0 = E[l]; e1 = E[l + 64];
    }
    float m = fminf(e0, e1);
#pragma unroll
    for (int off = 32; off > 0; off >>= 1) m = fminf(m, __shfl_xor(m, off));
    const float p0 = expf(m - e0);
    const float p1 = expf(m - e1);
    float s = p0 + p1;
#pragma unroll
    for (int off = 32; off > 0; off >>= 1) s += __shfl_xor(s, off);
    const float inv = 1.f / s;
    const size_t o = ((size_t)n * CN + i) * CN;
    unsigned int q0 = splitpack(p0 * inv), q1 = splitpack(p1 * inv);
    att_h[o + l]      = (unsigned short)(q0 & 0xffffu);
    att_l[o + l]      = (unsigned short)(q0 >> 16);
    att_h[o + l + 64] = (unsigned short)(q1 & 0xffffu);
    att_l[o + l + 64] = (unsigned short)(q1 >> 16);
}

// ---------------- K3: out = attn @ Q via MFMA, double-buffered ----------------
// grid (PB, NB), block 512. Per block: 256 s (4 chunks of 64).
// A = attn hi/lo in registers (from global, L2-resident). B = q-hi only
// (|Bl| <= 2^-9 |Bh|, attn row-sum = 1 -> dropped term ~0.2% of out, ok).
// LDS: 2 x [64 s][128 j] bf16 hi, pitch 256B, XOR-swizzled.  32 KB.
__global__ __launch_bounds__(512, 4) void pv_mfma(const float* __restrict__ x,
                                                  const unsigned short* __restrict__ att_h,
                                                  const unsigned short* __restrict__ att_l,
                                                  float* __restrict__ out) {
    __shared__ __align__(16) unsigned short qh[2][64 * CN];
    const int bx = blockIdx.x, n = blockIdx.y;
    const int tid = threadIdx.x;
    const int lane = tid & 63;
    const int w = tid >> 6;                 // wave -> i-tile (rows w*16..w*16+15)
    const int ra = lane & 15, kg = lane >> 4;

    // A-fragments from global
    bf16x8 a_h[4], a_l[4];
    {
        const size_t rowoff = ((size_t)n * CN + w * 16 + ra) * CN + kg * 8;
        const unsigned short* Ah = att_h + rowoff;
        const unsigned short* Al = att_l + rowoff;
#pragma unroll
        for (int kk = 0; kk < 4; ++kk) {
            a_h[kk] = *reinterpret_cast<const bf16x8*>(Ah + kk * 32);
            a_l[kk] = *reinterpret_cast<const bf16x8*>(Al + kk * 32);
        }
    }

    // staging mapping: thread -> 4x4 micro-block (j0..j0+3, s0..s0+3)
    const int j0 = (tid >> 4) * 4;          // 0..124
    const int s0 = (tid & 15) * 4;          // 0..60
    const float* gx = x + (size_t)n * CN * SN;
    const int sbase = bx * (PCH * 64);

    float4 st[4];
    auto load_chunk = [&](int sb) {
#pragma unroll
        for (int r = 0; r < 4; ++r)
            st[r] = *reinterpret_cast<const float4*>(gx + (size_t)(j0 + r) * SN + sb + s0);
    };

    auto stage = [&](int buf) {
        char* base = reinterpret_cast<char*>(qh[buf]);
#pragma unroll
        for (int r = 0; r < 4; ++r) {   // r = local s offset
            const int s = s0 + r;
            u16x4 hv;
            hv[0] = f2bh(r == 0 ? st[0].x : r == 1 ? st[0].y : r == 2 ? st[0].z : st[0].w);
            hv[1] = f2bh(r == 0 ? st[1].x : r == 1 ? st[1].y : r == 2 ? st[1].z : st[1].w);
            hv[2] = f2bh(r == 0 ? st[2].x : r == 1 ? st[2].y : r == 2 ? st[2].z : st[2].w);
            hv[3] = f2bh(r == 0 ? st[3].x : r == 1 ? st[3].y : r == 2 ? st[3].z : st[3].w);
            const int off = s * 256 + ((j0 * 2) ^ ((s & 7) << 4));
            *reinterpret_cast<u16x4*>(base + off) = hv;
        }
    };

    auto compute = [&](int buf, int sb) {
        const unsigned short* Q = qh[buf];
#pragma unroll
        for (int stile = 0; stile < 4; ++stile) {
            f32x4 acc = (f32x4){0.f, 0.f, 0.f, 0.f};
            const int srow = stile * 16 + ra;
#pragma unroll
            for (int kk = 0; kk < 4; ++kk) {
                const int kb = kk * 64 + (kg << 4);
                bf16x8 bh = ldsfrag(Q, srow, kb, 256);
                acc = mm(a_l[kk], bh, acc);
                acc = mm(a_h[kk], bh, acc);
            }
            float* o = out + ((size_t)n * CN + w * 16 + (kg << 2)) * SN + sb + stile * 16 + ra;
#pragma unroll
            for (int q = 0; q < 4; ++q) o[(size_t)q * SN] = acc[q];
        }
    };

    load_chunk(sbase);
    for (int t = 0; t < PCH; ++t) {
        stage(t & 1);
        if (t < PCH - 1) load_chunk(sbase + (t + 1) * 64);
        __syncthreads();
        compute(t & 1, sbase + t * 64);
    }
}

extern "C" void kernel_launch(void* const* d_in, const int* in_sizes, int n_in,
                              void* d_out, int out_size, void* d_ws, size_t ws_size,
                              hipStream_t stream) {
    (void)in_sizes; (void)n_in; (void)out_size;
    const float* x = (const float*)d_in[0];
    float* out = (float*)d_out;

    // ws: [energy 256KB][att_h 128KB][att_l 128KB][partials 16.8MB]
    float* energy = (float*)d_ws;
    unsigned short* att_h = (unsigned short*)(energy + (size_t)NB * CN * CN);
    unsigned short* att_l = att_h + (size_t)NB * CN * CN;
    float* part = (float*)(att_l + (size_t)NB * CN * CN);
    const size_t need =
        (size_t)NB * CN * CN * sizeof(float) +
        (size_t)NB * CN * CN * 2 * sizeof(unsigned short) +
        (size_t)NB * GB * CN * CN * sizeof(float);

    if (ws_size >= need) {
        gram_mfma<false><<<dim3(GB, NB), 512, 0, stream>>>(x, part);
        finish_kernel<true><<<dim3(CN, NB), 64, 0, stream>>>(part, att_h, att_l);
    } else {
        hipMemsetAsync(energy, 0, (size_t)NB * CN * CN * sizeof(float), stream);
        gram_mfma<true><<<dim3(GB, NB), 512, 0, stream>>>(x, energy);
        finish_kernel<false><<<dim3(CN, NB), 64, 0, stream>>>(energy, att_h, att_l);
    }
    pv_mfma<<<dim3(PB, NB), 512, 0, stream>>>(x, att_h, att_l, out);
}

// Round 4
// 141.792 us; speedup vs baseline: 3.6103x; 1.0064x over previous
//
#include <hip/hip_runtime.h>
#include <math.h>

// cSE channel self-attention, bf16-MFMA hi/lo, double-buffered.
// x: [N=4][C=128][S=110592] f32.  out: same shape f32.
// energy = Q Q^T; attn_ij = exp(rowmin - e_ij)/sum (== reference softmax(max-e));
// out = attn @ Q.

static constexpr int CN = 128;
static constexpr int SN = 110592;      // 48^3
static constexpr int NB = 4;

static constexpr int GB = 64;          // gram K-slices per batch (256 blocks = 1/CU)
static constexpr int GSL = SN / GB;    // 1728
static constexpr int GCH = GSL / 64;   // 27 chunks of K=64

static constexpr int PB = 432;         // pv s-blocks per batch (256 s each)
static constexpr int PCH = 4;          // chunks of 64 s per block

typedef float  f32x4  __attribute__((ext_vector_type(4)));
typedef short  bf16x8 __attribute__((ext_vector_type(8)));
typedef unsigned short u16x8 __attribute__((ext_vector_type(8)));
typedef unsigned short u16x4 __attribute__((ext_vector_type(4)));

// f32 -> (hi bf16, lo bf16) round-to-nearest-even, packed lo<<16|hi
__device__ __forceinline__ unsigned int splitpack(float v) {
    unsigned int u = __float_as_uint(v);
    unsigned int h = (u + 0x7fffu + ((u >> 16) & 1u)) >> 16;
    float lf = v - __uint_as_float(h << 16);
    unsigned int ul = __float_as_uint(lf);
    unsigned int l = (ul + 0x7fffu + ((ul >> 16) & 1u)) >> 16;
    return (l << 16) | (h & 0xffffu);
}
__device__ __forceinline__ unsigned short f2bh(float v) {
    unsigned int u = __float_as_uint(v);
    return (unsigned short)((u + 0x7fffu + ((u >> 16) & 1u)) >> 16);
}

// swizzled LDS fragment read: 16 B along k at given row
__device__ __forceinline__ bf16x8 ldsfrag(const unsigned short* base, int row, int kbyte, int pitchB) {
    const char* p = reinterpret_cast<const char*>(base) + row * pitchB + (kbyte ^ ((row & 7) << 4));
    return *reinterpret_cast<const bf16x8*>(p);
}
__device__ __forceinline__ f32x4 mm(bf16x8 a, bf16x8 b, f32x4 c) {
    return __builtin_amdgcn_mfma_f32_16x16x32_bf16(a, b, c, 0, 0, 0);
}

// ---------------- K1: Gram via MFMA, hi/lo split, double-buffered ----------------
// grid (GB, NB), block 512 (8 waves). Each block: K-slice of 1728, 27 chunks of 64.
// LDS: 2 x ([128 c][64 k] bf16 hi + lo), pitch 128B, XOR-swizzled.  64 KB total.
template <bool ATOMIC>
__global__ __launch_bounds__(512, 2) void gram_mfma(const float* __restrict__ x,
                                                    float* __restrict__ dst) {
    __shared__ __align__(16) unsigned short lh[2][CN * 64];
    __shared__ __align__(16) unsigned short ll[2][CN * 64];
    const int bx = blockIdx.x, n = blockIdx.y;
    const int tid = threadIdx.x;
    const int lane = tid & 63;
    const int w = tid >> 6;                // 0..7
    const int wr = w >> 2, wc = w & 3;     // wave grid 2x4
    const int ra = lane & 15, kg = lane >> 4;

    // staging mapping: thread -> (channel c, 16 consecutive k)
    const int c  = tid >> 2;               // 0..127
    const int ks = (tid & 3) << 4;         // 0,16,32,48
    const float* gq = x + (size_t)n * CN * SN + (size_t)c * SN + bx * GSL;

    f32x4 acc[4][2];
#pragma unroll
    for (int a = 0; a < 4; ++a)
#pragma unroll
        for (int b = 0; b < 2; ++b) acc[a][b] = (f32x4){0.f, 0.f, 0.f, 0.f};

    float4 st[4];
    auto load_chunk = [&](int t) {
        const float4* p = reinterpret_cast<const float4*>(gq + t * 64 + ks);
        st[0] = p[0]; st[1] = p[1]; st[2] = p[2]; st[3] = p[3];
    };

    auto stage = [&](int buf) {
        u16x8 ha, hb, la, lb;
        unsigned int p;
#define CV8(hv, lv, i, val) { p = splitpack(val); hv[i] = (unsigned short)(p & 0xffffu); lv[i] = (unsigned short)(p >> 16); }
        CV8(ha, la, 0, st[0].x) CV8(ha, la, 1, st[0].y) CV8(ha, la, 2, st[0].z) CV8(ha, la, 3, st[0].w)
        CV8(ha, la, 4, st[1].x) CV8(ha, la, 5, st[1].y) CV8(ha, la, 6, st[1].z) CV8(ha, la, 7, st[1].w)
        CV8(hb, lb, 0, st[2].x) CV8(hb, lb, 1, st[2].y) CV8(hb, lb, 2, st[2].z) CV8(hb, lb, 3, st[2].w)
        CV8(hb, lb, 4, st[3].x) CV8(hb, lb, 5, st[3].y) CV8(hb, lb, 6, st[3].z) CV8(hb, lb, 7, st[3].w)
#undef CV8
        char* ph = reinterpret_cast<char*>(lh[buf]) + c * 128;
        char* pl = reinterpret_cast<char*>(ll[buf]) + c * 128;
        const int sw = (c & 7) << 4;
        const int k2 = ks * 2;
        *reinterpret_cast<u16x8*>(ph + (k2 ^ sw))        = ha;
        *reinterpret_cast<u16x8*>(ph + ((k2 + 16) ^ sw)) = hb;
        *reinterpret_cast<u16x8*>(pl + (k2 ^ sw))        = la;
        *reinterpret_cast<u16x8*>(pl + ((k2 + 16) ^ sw)) = lb;
    };

    auto compute = [&](int buf) {
        const unsigned short* LH = lh[buf];
        const unsigned short* LL = ll[buf];
#pragma unroll
        for (int kk = 0; kk < 2; ++kk) {
            const int kb = kk * 64 + (kg << 4);
            bf16x8 ah[4], al[4], bh[2], bl[2];
#pragma unroll
            for (int it = 0; it < 4; ++it) {
                const int row = wr * 64 + it * 16 + ra;
                ah[it] = ldsfrag(LH, row, kb, 128);
                al[it] = ldsfrag(LL, row, kb, 128);
            }
#pragma unroll
            for (int jt = 0; jt < 2; ++jt) {
                const int row = wc * 32 + jt * 16 + ra;
                bh[jt] = ldsfrag(LH, row, kb, 128);
                bl[jt] = ldsfrag(LL, row, kb, 128);
            }
#pragma unroll
            for (int it = 0; it < 4; ++it)
#pragma unroll
                for (int jt = 0; jt < 2; ++jt) {
                    acc[it][jt] = mm(ah[it], bh[jt], acc[it][jt]);
                    acc[it][jt] = mm(ah[it], bl[jt], acc[it][jt]);
                    acc[it][jt] = mm(al[it], bh[jt], acc[it][jt]);
                }
        }
    };

    load_chunk(0);
    for (int t = 0; t < GCH; ++t) {
        stage(t & 1);
        if (t < GCH - 1) load_chunk(t + 1);   // prefetch overlaps MFMA
        __syncthreads();                      // single barrier per chunk (dbuf)
        compute(t & 1);
    }

    // epilogue: C/D map row=(lane>>4)*4+q, col=lane&15
    const int q4 = kg << 2;
    if (!ATOMIC) {
        float* P = dst + (size_t)(n * GB + bx) * (CN * CN);
#pragma unroll
        for (int it = 0; it < 4; ++it)
#pragma unroll
            for (int jt = 0; jt < 2; ++jt)
#pragma unroll
                for (int q = 0; q < 4; ++q)
                    P[(wr * 64 + it * 16 + q4 + q) * CN + wc * 32 + jt * 16 + ra] = acc[it][jt][q];
    } else {
        float* E = dst + (size_t)n * CN * CN;
#pragma unroll
        for (int it = 0; it < 4; ++it)
#pragma unroll
            for (int jt = 0; jt < 2; ++jt)
#pragma unroll
                for (int q = 0; q < 4; ++q)
                    atomicAdd(&E[(wr * 64 + it * 16 + q4 + q) * CN + wc * 32 + jt * 16 + ra], acc[it][jt][q]);
    }
}

// ---------------- K2: fused reduce + softmin -> bf16 hi/lo attention ----------------
// grid (CN, NB), block 64 (one wave per row). Deterministic fixed-order k sum.
template <bool REDUCE>
__global__ void finish_kernel(const float* __restrict__ src,
                              unsigned short* __restrict__ att_h,
                              unsigned short* __restrict__ att_l) {
    const int i = blockIdx.x, n = blockIdx.y, l = threadIdx.x;
    float e0, e1;
    if (REDUCE) {
        const float* p = src + (size_t)n * GB * (CN * CN) + i * CN;
        e0 = 0.f; e1 = 0.f;
#pragma unroll 8
        for (int k = 0; k < GB; ++k) {
            e0 += p[(size_t)k * (CN * CN) + l];
            e1 += p[(size_t)k * (CN * CN) + l + 64];
        }
    } else {
        const float* E = src + ((size_t)n * CN + i) * CN;
        e0 = E[l]; e1 = E[l + 64];
    }
    float m = fminf(e0, e1);
#pragma unroll
    for (int off = 32; off > 0; off >>= 1) m = fminf(m, __shfl_xor(m, off));
    const float p0 = expf(m - e0);
    const float p1 = expf(m - e1);
    float s = p0 + p1;
#pragma unroll
    for (int off = 32; off > 0; off >>= 1) s += __shfl_xor(s, off);
    const float inv = 1.f / s;
    const size_t o = ((size_t)n * CN + i) * CN;
    unsigned int q0 = splitpack(p0 * inv), q1 = splitpack(p1 * inv);
    att_h[o + l]      = (unsigned short)(q0 & 0xffffu);
    att_l[o + l]      = (unsigned short)(q0 >> 16);
    att_h[o + l + 64] = (unsigned short)(q1 & 0xffffu);
    att_l[o + l + 64] = (unsigned short)(q1 >> 16);
}

// ---------------- K3: out = attn @ Q via MFMA, double-buffered ----------------
// grid (PB, NB), block 512. Per block: 256 s (4 chunks of 64).
// A = attn hi/lo in registers (from global, L2-resident). B = q-hi only
// (|Bl| <= 2^-9 |Bh|, attn row-sum = 1 -> dropped term ~0.2% of out, ok).
// LDS: 2 x [64 s][128 j] bf16 hi, pitch 256B, XOR-swizzled.  32 KB.
__global__ __launch_bounds__(512, 4) void pv_mfma(const float* __restrict__ x,
                                                  const unsigned short* __restrict__ att_h,
                                                  const unsigned short* __restrict__ att_l,
                                                  float* __restrict__ out) {
    __shared__ __align__(16) unsigned short qh[2][64 * CN];
    const int bx = blockIdx.x, n = blockIdx.y;
    const int tid = threadIdx.x;
    const int lane = tid & 63;
    const int w = tid >> 6;                 // wave -> i-tile (rows w*16..w*16+15)
    const int ra = lane & 15, kg = lane >> 4;

    // A-fragments from global
    bf16x8 a_h[4], a_l[4];
    {
        const size_t rowoff = ((size_t)n * CN + w * 16 + ra) * CN + kg * 8;
        const unsigned short* Ah = att_h + rowoff;
        const unsigned short* Al = att_l + rowoff;
#pragma unroll
        for (int kk = 0; kk < 4; ++kk) {
            a_h[kk] = *reinterpret_cast<const bf16x8*>(Ah + kk * 32);
            a_l[kk] = *reinterpret_cast<const bf16x8*>(Al + kk * 32);
        }
    }

    // staging mapping: thread -> 4x4 micro-block (j0..j0+3, s0..s0+3)
    const int j0 = (tid >> 4) * 4;          // 0..124
    const int s0 = (tid & 15) * 4;          // 0..60
    const float* gx = x + (size_t)n * CN * SN;
    const int sbase = bx * (PCH * 64);

    float4 st[4];
    auto load_chunk = [&](int sb) {
#pragma unroll
        for (int r = 0; r < 4; ++r)
            st[r] = *reinterpret_cast<const float4*>(gx + (size_t)(j0 + r) * SN + sb + s0);
    };

    auto stage = [&](int buf) {
        char* base = reinterpret_cast<char*>(qh[buf]);
#pragma unroll
        for (int r = 0; r < 4; ++r) {   // r = local s offset
            const int s = s0 + r;
            u16x4 hv;
            hv[0] = f2bh(r == 0 ? st[0].x : r == 1 ? st[0].y : r == 2 ? st[0].z : st[0].w);
            hv[1] = f2bh(r == 0 ? st[1].x : r == 1 ? st[1].y : r == 2 ? st[1].z : st[1].w);
            hv[2] = f2bh(r == 0 ? st[2].x : r == 1 ? st[2].y : r == 2 ? st[2].z : st[2].w);
            hv[3] = f2bh(r == 0 ? st[3].x : r == 1 ? st[3].y : r == 2 ? st[3].z : st[3].w);
            const int off = s * 256 + ((j0 * 2) ^ ((s & 7) << 4));
            *reinterpret_cast<u16x4*>(base + off) = hv;
        }
    };

    auto compute = [&](int buf, int sb) {
        const unsigned short* Q = qh[buf];
#pragma unroll
        for (int stile = 0; stile < 4; ++stile) {
            f32x4 acc = (f32x4){0.f, 0.f, 0.f, 0.f};
            const int srow = stile * 16 + ra;
#pragma unroll
            for (int kk = 0; kk < 4; ++kk) {
                const int kb = kk * 64 + (kg << 4);
                bf16x8 bh = ldsfrag(Q, srow, kb, 256);
                acc = mm(a_l[kk], bh, acc);
                acc = mm(a_h[kk], bh, acc);
            }
            float* o = out + ((size_t)n * CN + w * 16 + (kg << 2)) * SN + sb + stile * 16 + ra;
#pragma unroll
            for (int q = 0; q < 4; ++q) o[(size_t)q * SN] = acc[q];
        }
    };

    load_chunk(sbase);
    for (int t = 0; t < PCH; ++t) {
        stage(t & 1);
        if (t < PCH - 1) load_chunk(sbase + (t + 1) * 64);
        __syncthreads();
        compute(t & 1, sbase + t * 64);
    }
}

extern "C" void kernel_launch(void* const* d_in, const int* in_sizes, int n_in,
                              void* d_out, int out_size, void* d_ws, size_t ws_size,
                              hipStream_t stream) {
    (void)in_sizes; (void)n_in; (void)out_size;
    const float* x = (const float*)d_in[0];
    float* out = (float*)d_out;

    // ws: [energy 256KB][att_h 128KB][att_l 128KB][partials 16.8MB]
    float* energy = (float*)d_ws;
    unsigned short* att_h = (unsigned short*)(energy + (size_t)NB * CN * CN);
    unsigned short* att_l = att_h + (size_t)NB * CN * CN;
    float* part = (float*)(att_l + (size_t)NB * CN * CN);
    const size_t need =
        (size_t)NB * CN * CN * sizeof(float) +
        (size_t)NB * CN * CN * 2 * sizeof(unsigned short) +
        (size_t)NB * GB * CN * CN * sizeof(float);

    if (ws_size >= need) {
        gram_mfma<false><<<dim3(GB, NB), 512, 0, stream>>>(x, part);
        finish_kernel<true><<<dim3(CN, NB), 64, 0, stream>>>(part, att_h, att_l);
    } else {
        hipMemsetAsync(energy, 0, (size_t)NB * CN * CN * sizeof(float), stream);
        gram_mfma<true><<<dim3(GB, NB), 512, 0, stream>>>(x, energy);
        finish_kernel<false><<<dim3(CN, NB), 64, 0, stream>>>(energy, att_h, att_l);
    }
    pv_mfma<<<dim3(PB, NB), 512, 0, stream>>>(x, att_h, att_l, out);
}